// Round 10
// baseline (93.834 us; speedup 1.0000x reference)
//
#include <hip/hip_runtime.h>

#define BB 8
#define XX 256
#define CC 256
#define TCD 8         // c-rows per k_dist block
#define TCE 4         // c-rows per k_epi block
#define TD 4          // d's per lane (float4 d-loads) -> wave covers 256 d
#define SPLIT 16      // x-chunks; XH=16
#define XH (XX / SPLIT)
#define GX 4          // x-group for register double-buffer (4 b128 loads in flight x2)

// R10: kill the scalar d-column load stream. R6-R9 invariant ~24 us traced to
// 262k wave-loads of 256 B (b32/lane, stride-1KB, no L1 reuse, ~200cyc L2).
// Lane now owns 4 consecutive d -> one b128 1KB/wave coalesced load per x;
// 4x fewer load instrs, 4x more FMA per load. Per-(c,d) FMA chain, x-order,
// and partial formula bitwise unchanged; only chunk granularity 64->16 and
// 16-way sequential combine differ (ulp-class, same category as R5/R6
// reformulations that scored absmax 0.0).

// ---------------- Path A ----------------

// k_u: u = wa*amp + wp*ph for all B*X*C; blocks 0..63 also zero `out`.
__global__ __launch_bounds__(256) void k_u(
    const float* __restrict__ amp, const float* __restrict__ ph,
    const float* __restrict__ wAp, const float* __restrict__ wPp,
    float* __restrict__ u, float* __restrict__ out)
{
    const float wa = wAp[0], wp = wPp[0];
    const int i = blockIdx.x * 256 + threadIdx.x;   // float4 index, exact cover
    const float4 a = ((const float4*)amp)[i];
    const float4 p = ((const float4*)ph)[i];
    float4 r;
    r.x = __fadd_rn(__fmul_rn(wa, a.x), __fmul_rn(wp, p.x));
    r.y = __fadd_rn(__fmul_rn(wa, a.y), __fmul_rn(wp, p.y));
    r.z = __fadd_rn(__fmul_rn(wa, a.z), __fmul_rn(wp, p.z));
    r.w = __fadd_rn(__fmul_rn(wa, a.w), __fmul_rn(wp, p.w));
    ((float4*)u)[i] = r;

    if (blockIdx.x < 64) {            // 64 blocks * 256 thr * 16B = 256 KB = out
        ((float4*)out)[blockIdx.x * 256 + threadIdx.x] = make_float4(0.f, 0.f, 0.f, 0.f);
    }
}

// load a group of GX x's: one b128 per x (lane l -> d=4l..4l+3)
#define ULOAD4(BU, GIDX) {                                        \
    const float* _p = ud_base + (size_t)(GIDX) * GX * CC;         \
    _Pragma("unroll")                                             \
    for (int i = 0; i < GX; ++i)                                  \
        BU[i] = *(const float4*)(_p + (size_t)i * CC);            }

// consume a group: 8c x 4d FMA + 4 sacc FMA per x, x ascending
#define UCOMP4(BU, GIDX) {                                        \
    const int _xb = xloc + (GIDX) * GX;                           \
    _Pragma("unroll")                                             \
    for (int i = 0; i < GX; ++i) {                                \
        const float4 ud4 = BU[i];                                 \
        const float4 cA = cols[_xb + i][0];                       \
        const float4 cB = cols[_xb + i][1];                       \
        _Pragma("unroll")                                         \
        for (int k = 0; k < 4; ++k) {                             \
            const float uv = (k==0)?ud4.x:(k==1)?ud4.y:(k==2)?ud4.z:ud4.w; \
            gacc[0][k] = fmaf(cA.x, uv, gacc[0][k]);              \
            gacc[1][k] = fmaf(cA.y, uv, gacc[1][k]);              \
            gacc[2][k] = fmaf(cA.z, uv, gacc[2][k]);              \
            gacc[3][k] = fmaf(cA.w, uv, gacc[3][k]);              \
            gacc[4][k] = fmaf(cB.x, uv, gacc[4][k]);              \
            gacc[5][k] = fmaf(cB.y, uv, gacc[5][k]);              \
            gacc[6][k] = fmaf(cB.z, uv, gacc[6][k]);              \
            gacc[7][k] = fmaf(cB.w, uv, gacc[7][k]);              \
            sacc[k]    = fmaf(uv, uv, sacc[k]);                   \
        }                                                         \
    } }

__global__ __launch_bounds__(256, 4) void k_dist(
    const float* __restrict__ u,      // (B,X,C) in ws
    float* __restrict__ wsd)          // [SPLIT][B][C][C] partials
{
    const int tid  = threadIdx.x;
    const int lane = tid & 63;
    const int w    = tid >> 6;            // wave 0..3 -> chunk cz
    const int c0   = blockIdx.x * TCD;
    const int b    = blockIdx.y;
    const int cz   = blockIdx.z * 4 + w;  // chunk id 0..15
    const int x0b  = blockIdx.z * 64;     // block's contiguous 64-x window
    const int xloc = w * XH;              // wave's x-offset within window
    const int d0   = lane * TD;           // this lane's first d

    // stage c-columns for the block's 64-x window (R7-proven LDS path)
    __shared__ float4 cols[64][2];        // u[b, x0b+x, c0..c0+7]  2 KB
    if (tid < 128) {
        const int x = tid >> 1, h = tid & 1;
        cols[x][h] = *(const float4*)(u + ((size_t)b * XX + x0b + x) * CC + c0 + 4 * h);
    }
    __syncthreads();

    const float* ud_base = u + ((size_t)b * XX + x0b + xloc) * CC + d0;

    float gacc[TCD][4];
#pragma unroll
    for (int j = 0; j < TCD; ++j)
#pragma unroll
        for (int k = 0; k < 4; ++k) gacc[j][k] = 0.0f;
    float sacc[4] = {0.f, 0.f, 0.f, 0.f};

    constexpr int NG = XH / GX;           // 4 groups of 4 x
    {
        float4 b0[GX], b1[GX];
        ULOAD4(b0, 0)
        ULOAD4(b1, 1)
        UCOMP4(b0, 0)
        ULOAD4(b0, 2)
        UCOMP4(b1, 1)
        ULOAD4(b1, 3)
        UCOMP4(b0, 2)
        UCOMP4(b1, 3)
        static_assert(NG == 4, "pipeline hard-coded for NG==4");
    }

    // exchange S within the wave's chunk: sS[w][d]
    __shared__ float sS[4][CC];           // 4 KB
    *(float4*)&sS[w][d0] = make_float4(sacc[0], sacc[1], sacc[2], sacc[3]);
    __syncthreads();

    // partial = fmaf(-2, G, S_c + S_d)  — same formula as R7, per 16-x chunk
    float* wbase = wsd + (((size_t)cz * BB + b) * CC + c0) * CC + d0;
#pragma unroll
    for (int j = 0; j < TCD; ++j) {
        const float scj = sS[w][c0 + j];
        float4 o;
        o.x = fmaf(-2.0f, gacc[j][0], __fadd_rn(scj, sacc[0]));
        o.y = fmaf(-2.0f, gacc[j][1], __fadd_rn(scj, sacc[1]));
        o.z = fmaf(-2.0f, gacc[j][2], __fadd_rn(scj, sacc[2]));
        o.w = fmaf(-2.0f, gacc[j][3], __fadd_rn(scj, sacc[3]));
        *(float4*)(wbase + (size_t)j * CC) = o;   // coalesced b128 store
    }
}

__global__ __launch_bounds__(256, 4) void k_epi(
    const float* __restrict__ wsd, const float* __restrict__ A,
    const float* __restrict__ gu,  float* __restrict__ out)
{
    const int d  = threadIdx.x;
    const int c0 = blockIdx.x * TCE;
    const int b  = blockIdx.y;

    const float dAd  = A[(size_t)d * CC + d];
    const float dAd2 = __fmul_rn(dAd, dAd);

    // pre-issue all 64 partial loads, then combine sequentially per j
    float pv[TCE][SPLIT];
#pragma unroll
    for (int j = 0; j < TCE; ++j) {
        const size_t ro = ((size_t)b * CC + c0 + j) * CC + d;
#pragma unroll
        for (int h = 0; h < SPLIT; ++h)
            pv[j][h] = wsd[(size_t)h * BB * CC * CC + ro];
    }

    float dist[TCE];
#pragma unroll
    for (int j = 0; j < TCE; ++j) {
        float p = pv[j][0];
#pragma unroll
        for (int h = 1; h < SPLIT; ++h) p = __fadd_rn(p, pv[j][h]);
        dist[j] = __fmul_rn(dAd2, p);
    }

    float ed[TCE];
#pragma unroll
    for (int j = 0; j < TCE; ++j)
        ed[j] = (d == c0 + j) ? 0.0f : __fdiv_rn(1.0f, __fadd_rn(dist[j], 1e-10f));

    __shared__ float wmax[TCE][4];
    const int wave = threadIdx.x >> 6;
    const int lane = threadIdx.x & 63;
#pragma unroll
    for (int j = 0; j < TCE; ++j) {
        float v = ed[j];
#pragma unroll
        for (int m = 1; m < 64; m <<= 1) v = fmaxf(v, __shfl_xor(v, m));
        if (lane == 0) wmax[j][wave] = v;
    }
    __syncthreads();

#pragma unroll
    for (int j = 0; j < TCE; ++j) {
        const int c = c0 + j;
        float em = fmaxf(fmaxf(wmax[j][0], wmax[j][1]), fmaxf(wmax[j][2], wmax[j][3]));
        float p;
        if (d == c) {
            p = 0.99f;
        } else {
            p = __fmul_rn(__fdiv_rn(ed[j], em), 0.99f);
        }
        float logit = logf(__fdiv_rn(p, __fsub_rn(1.0f, p)));

        const float2 g2 = *(const float2*)(gu + (((size_t)b * CC + c) * CC + d) * 2);
        float g0 = -logf(-logf(g2.x));
        float g1 = -logf(-logf(g2.y));

        float a0 = __fadd_rn(logit, g0);
        float a1 = __fadd_rn(-logit, g1);
        float m  = fmaxf(a0, a1);
        float e0 = expf(__fsub_rn(a0, m));
        float e1 = expf(__fsub_rn(a1, m));
        float s  = __fadd_rn(e0, e1);
        float y0 = __fdiv_rn(e0, s);
        float y1 = __fdiv_rn(e1, s);
        if (y0 > y1) {
            atomicAdd(&out[(size_t)c * CC + d], 0.125f);
        }
    }
}

// ---------------- Path B: fused fallback (no ws) — R7 verbatim ----------------

#define STEPU(UC, ACC) {                         \
    float diff = __fsub_rn(UC, ud);              \
    float t    = __fmul_rn(dAd, diff);           \
    float sq   = __fmul_rn(t, t);                \
    ACC = __fadd_rn(ACC, sq);                    \
}

#define LOADG(BA, BP, GIDX) {                    \
    const float* _a = ampbd + (size_t)(GIDX) * 8 * CC; \
    const float* _p = phbd  + (size_t)(GIDX) * 8 * CC; \
    _Pragma("unroll")                            \
    for (int i = 0; i < 8; ++i) {                \
        BA[i] = _a[(size_t)i * CC];              \
        BP[i] = _p[(size_t)i * CC];              \
    }                                            \
}

#define COMPG(BA, BP, GIDX) {                    \
    const int _xb = (GIDX) * 8;                  \
    _Pragma("unroll")                            \
    for (int i = 0; i < 8; ++i) {                \
        const float av = BA[i];                  \
        const float pv = BP[i];                  \
        const float ud = __fadd_rn(__fmul_rn(wa, av), __fmul_rn(wp, pv)); \
        const float4 uc = cols[_xb + i];         \
        STEPU(uc.x, acc0)                        \
        STEPU(uc.y, acc1)                        \
        STEPU(uc.z, acc2)                        \
        STEPU(uc.w, acc3)                        \
    }                                            \
}

__global__ __launch_bounds__(256, 2) void k_fused(
    const float* __restrict__ amp, const float* __restrict__ ph,
    const float* __restrict__ A,   const float* __restrict__ wAp,
    const float* __restrict__ wPp, const float* __restrict__ gu,
    float* __restrict__ out)
{
    const int d  = threadIdx.x;
    const int c0 = blockIdx.x * TCE;
    const int b  = blockIdx.y;

    const float wa = wAp[0];
    const float wp = wPp[0];

    __shared__ float4 cols[XX];
    {
        const int x = threadIdx.x;
        const size_t base = ((size_t)b * XX + x) * CC + c0;
        const float4 a4 = *(const float4*)(amp + base);
        const float4 p4 = *(const float4*)(ph  + base);
        float4 uu;
        uu.x = __fadd_rn(__fmul_rn(wa, a4.x), __fmul_rn(wp, p4.x));
        uu.y = __fadd_rn(__fmul_rn(wa, a4.y), __fmul_rn(wp, p4.y));
        uu.z = __fadd_rn(__fmul_rn(wa, a4.z), __fmul_rn(wp, p4.z));
        uu.w = __fadd_rn(__fmul_rn(wa, a4.w), __fmul_rn(wp, p4.w));
        cols[x] = uu;
    }
    __syncthreads();

    const float dAd = A[(size_t)d * CC + d];
    const float* ampbd = amp + (size_t)b * XX * CC + d;
    const float* phbd  = ph  + (size_t)b * XX * CC + d;

    float acc0 = 0.0f, acc1 = 0.0f, acc2 = 0.0f, acc3 = 0.0f;
    constexpr int NG = XX / 8;
    {
        float b0A[8], b0P[8], b1A[8], b1P[8];
        LOADG(b0A, b0P, 0)
        for (int g = 0; g + 2 < NG; g += 2) {
            LOADG(b1A, b1P, g + 1)
            COMPG(b0A, b0P, g)
            LOADG(b0A, b0P, g + 2)
            COMPG(b1A, b1P, g + 1)
        }
        LOADG(b1A, b1P, NG - 1)
        COMPG(b0A, b0P, NG - 2)
        COMPG(b1A, b1P, NG - 1)
    }

    float ed[TCE];
    ed[0] = (d == c0)     ? 0.0f : __fdiv_rn(1.0f, __fadd_rn(acc0, 1e-10f));
    ed[1] = (d == c0 + 1) ? 0.0f : __fdiv_rn(1.0f, __fadd_rn(acc1, 1e-10f));
    ed[2] = (d == c0 + 2) ? 0.0f : __fdiv_rn(1.0f, __fadd_rn(acc2, 1e-10f));
    ed[3] = (d == c0 + 3) ? 0.0f : __fdiv_rn(1.0f, __fadd_rn(acc3, 1e-10f));

    __shared__ float wmax[TCE][4];
    const int wave = threadIdx.x >> 6;
    const int lane = threadIdx.x & 63;
#pragma unroll
    for (int j = 0; j < TCE; ++j) {
        float v = ed[j];
#pragma unroll
        for (int m = 1; m < 64; m <<= 1) v = fmaxf(v, __shfl_xor(v, m));
        if (lane == 0) wmax[j][wave] = v;
    }
    __syncthreads();

#pragma unroll
    for (int j = 0; j < TCE; ++j) {
        const int c = c0 + j;
        float em = fmaxf(fmaxf(wmax[j][0], wmax[j][1]), fmaxf(wmax[j][2], wmax[j][3]));
        float p;
        if (d == c) {
            p = 0.99f;
        } else {
            p = __fmul_rn(__fdiv_rn(ed[j], em), 0.99f);
        }
        float logit = logf(__fdiv_rn(p, __fsub_rn(1.0f, p)));

        const float2 g2 = *(const float2*)(gu + (((size_t)b * CC + c) * CC + d) * 2);
        float g0 = -logf(-logf(g2.x));
        float g1 = -logf(-logf(g2.y));

        float a0 = __fadd_rn(logit, g0);
        float a1 = __fadd_rn(-logit, g1);
        float m  = fmaxf(a0, a1);
        float e0 = expf(__fsub_rn(a0, m));
        float e1 = expf(__fsub_rn(a1, m));
        float s  = __fadd_rn(e0, e1);
        float y0 = __fdiv_rn(e0, s);
        float y1 = __fdiv_rn(e1, s);
        if (y0 > y1) {
            atomicAdd(&out[(size_t)c * CC + d], 0.125f);
        }
    }
}

extern "C" void kernel_launch(void* const* d_in, const int* in_sizes, int n_in,
                              void* d_out, int out_size, void* d_ws, size_t ws_size,
                              hipStream_t stream) {
    const float* amp = (const float*)d_in[0];
    const float* ph  = (const float*)d_in[1];
    const float* A   = (const float*)d_in[2];
    const float* wa  = (const float*)d_in[3];
    const float* wp  = (const float*)d_in[4];
    const float* gu  = (const float*)d_in[5];
    float* out = (float*)d_out;

    const size_t uElems = (size_t)BB * XX * CC;                    // 2 MB
    const size_t pElems = (size_t)SPLIT * BB * CC * CC;            // 32 MB
    const size_t need = (uElems + pElems) * sizeof(float);
    if (ws_size >= need) {
        float* ud  = (float*)d_ws;          // fully written by k_u
        float* wsd = ud + uElems;           // fully written by k_dist
        k_u<<<uElems / 4 / 256, 256, 0, stream>>>(amp, ph, wa, wp, ud, out);
        dim3 g1(CC / TCD, BB, SPLIT / 4);
        k_dist<<<g1, 256, 0, stream>>>(ud, wsd);
        dim3 g2(CC / TCE, BB);
        k_epi<<<g2, 256, 0, stream>>>(wsd, A, gu, out);
    } else {
        hipMemsetAsync(out, 0, (size_t)CC * CC * sizeof(float), stream);
        dim3 g(CC / TCE, BB);
        k_fused<<<g, 256, 0, stream>>>(amp, ph, A, wa, wp, gu, out);
    }
}

// Round 11
// 89.953 us; speedup vs baseline: 1.0431x; 1.0431x over previous
//
#include <hip/hip_runtime.h>

#define BB 8
#define XX 256
#define CC 256
#define TCD 2         // c-rows per k_dist block (lane owns 4 d's -> 2c x 4d = 8 G-FMA/x)
#define TCE 4         // c-rows per k_epi block (R7 verbatim)
#define TD 4          // d's per lane -> wave covers all 256 d, b128 d-loads
#define SPLIT 4       // x-chunks of 64 (R7 granularity -> wsd bitwise R7)
#define XH (XX / SPLIT)
#define GX 4          // x-group for register double-buffer

// R11 = R7 bitwise output, with the one structural fix R10 fumbled:
// TD=4 d-vectorization cuts the col-broadcast instruction stream 4x
// (524288 -> 131072) — the R7/R9-invariant ~10us cost that lived on the DS
// pipe (R7) or VMEM pipe (R9). SPLIT stays 4 (8MB wsd, 64-x chunks) and
// k_epi stays R7-verbatim, undoing R10's 32MB wsd + 64-load k_epi mistakes.

// ---------------- k_u: u = wa*amp + wp*ph; blocks 0..63 zero `out` ----------------

__global__ __launch_bounds__(256) void k_u(
    const float* __restrict__ amp, const float* __restrict__ ph,
    const float* __restrict__ wAp, const float* __restrict__ wPp,
    float* __restrict__ u, float* __restrict__ out)
{
    const float wa = wAp[0], wp = wPp[0];
    const int i = blockIdx.x * 256 + threadIdx.x;   // float4 index, exact cover
    const float4 a = ((const float4*)amp)[i];
    const float4 p = ((const float4*)ph)[i];
    float4 r;
    r.x = __fadd_rn(__fmul_rn(wa, a.x), __fmul_rn(wp, p.x));
    r.y = __fadd_rn(__fmul_rn(wa, a.y), __fmul_rn(wp, p.y));
    r.z = __fadd_rn(__fmul_rn(wa, a.z), __fmul_rn(wp, p.z));
    r.w = __fadd_rn(__fmul_rn(wa, a.w), __fmul_rn(wp, p.w));
    ((float4*)u)[i] = r;

    if (blockIdx.x < 64) {            // 64 blocks * 256 thr * 16B = 256 KB = out
        ((float4*)out)[blockIdx.x * 256 + threadIdx.x] = make_float4(0.f, 0.f, 0.f, 0.f);
    }
}

// ---------------- k_dist: TD=4 Gram partials, 64-x chunks ----------------

#define ULOAD(BU, GIDX) {                                         \
    const float* _p = ud_base + (size_t)(GIDX) * GX * CC;         \
    _Pragma("unroll")                                             \
    for (int i = 0; i < GX; ++i)                                  \
        BU[i] = *(const float4*)(_p + (size_t)i * CC);            }

#define UCOMP(BU, GIDX) {                                         \
    const int _xb = xloc + (GIDX) * GX;                           \
    _Pragma("unroll")                                             \
    for (int i = 0; i < GX; ++i) {                                \
        const float4 ud4 = BU[i];                                 \
        const float2 cc  = cols[_xb + i];                         \
        g00 = fmaf(cc.x, ud4.x, g00);                             \
        g01 = fmaf(cc.x, ud4.y, g01);                             \
        g02 = fmaf(cc.x, ud4.z, g02);                             \
        g03 = fmaf(cc.x, ud4.w, g03);                             \
        g10 = fmaf(cc.y, ud4.x, g10);                             \
        g11 = fmaf(cc.y, ud4.y, g11);                             \
        g12 = fmaf(cc.y, ud4.z, g12);                             \
        g13 = fmaf(cc.y, ud4.w, g13);                             \
        s0  = fmaf(ud4.x, ud4.x, s0);                             \
        s1  = fmaf(ud4.y, ud4.y, s1);                             \
        s2  = fmaf(ud4.z, ud4.z, s2);                             \
        s3  = fmaf(ud4.w, ud4.w, s3);                             \
    } }

__global__ __launch_bounds__(256, 4) void k_dist(
    const float* __restrict__ u,      // (B,X,C) in ws
    float* __restrict__ wsd)          // [SPLIT][B][C][C] partials
{
    const int tid  = threadIdx.x;
    const int lane = tid & 63;
    const int w    = tid >> 6;            // wave -> x-chunk 0..3
    const int c0   = blockIdx.x * TCD;
    const int b    = blockIdx.y;
    const int xloc = w * XH;              // wave's 64-x window
    const int d0   = lane * TD;

    // stage both c-columns for all 256 x (2 KB); broadcast b64 reads later
    __shared__ float2 cols[XX];
    if (tid < XX) {
        const float* cp = u + ((size_t)b * XX + tid) * CC + c0;
        cols[tid] = make_float2(cp[0], cp[1]);
    }
    __syncthreads();

    const float* ud_base = u + ((size_t)b * XX + xloc) * CC + d0;

    float g00=0.f,g01=0.f,g02=0.f,g03=0.f;
    float g10=0.f,g11=0.f,g12=0.f,g13=0.f;
    float s0=0.f,s1=0.f,s2=0.f,s3=0.f;

    constexpr int NG = XH / GX;           // 16 groups of 4 x
    {
        float4 b0[GX], b1[GX];
        ULOAD(b0, 0)
        for (int g = 0; g + 2 < NG; g += 2) {
            ULOAD(b1, g + 1)
            UCOMP(b0, g)
            ULOAD(b0, g + 2)
            UCOMP(b1, g + 1)
        }
        ULOAD(b1, NG - 1)
        UCOMP(b0, NG - 2)
        UCOMP(b1, NG - 1)
    }

    // per-chunk S exchange: sS[w][d]
    __shared__ float sS[4][CC];           // 4 KB
    *(float4*)&sS[w][d0] = make_float4(s0, s1, s2, s3);
    __syncthreads();

    const float sc0 = sS[w][c0];
    const float sc1 = sS[w][c0 + 1];

    // partial = fmaf(-2, G, S_c + S_d)  — bitwise R7 per (c,d,chunk)
    float* wbase = wsd + (((size_t)w * BB + b) * CC + c0) * CC + d0;
    float4 o0, o1;
    o0.x = fmaf(-2.0f, g00, __fadd_rn(sc0, s0));
    o0.y = fmaf(-2.0f, g01, __fadd_rn(sc0, s1));
    o0.z = fmaf(-2.0f, g02, __fadd_rn(sc0, s2));
    o0.w = fmaf(-2.0f, g03, __fadd_rn(sc0, s3));
    o1.x = fmaf(-2.0f, g10, __fadd_rn(sc1, s0));
    o1.y = fmaf(-2.0f, g11, __fadd_rn(sc1, s1));
    o1.z = fmaf(-2.0f, g12, __fadd_rn(sc1, s2));
    o1.w = fmaf(-2.0f, g13, __fadd_rn(sc1, s3));
    *(float4*)(wbase)          = o0;      // coalesced b128 stores
    *(float4*)(wbase + CC)     = o1;
}

// ---------------- k_epi: R7 verbatim ----------------

__global__ __launch_bounds__(256, 4) void k_epi(
    const float* __restrict__ wsd, const float* __restrict__ A,
    const float* __restrict__ gu,  float* __restrict__ out)
{
    const int d  = threadIdx.x;
    const int c0 = blockIdx.x * TCE;
    const int b  = blockIdx.y;

    const float dAd  = A[(size_t)d * CC + d];
    const float dAd2 = __fmul_rn(dAd, dAd);

    float dist[TCE];
#pragma unroll
    for (int j = 0; j < TCE; ++j) {
        const size_t ro = ((size_t)b * CC + c0 + j) * CC + d;
        float p = wsd[ro];                                    // chunk 0
#pragma unroll
        for (int h = 1; h < SPLIT; ++h)
            p = __fadd_rn(p, wsd[(size_t)h * BB * CC * CC + ro]);
        dist[j] = __fmul_rn(dAd2, p);
    }

    float ed[TCE];
#pragma unroll
    for (int j = 0; j < TCE; ++j)
        ed[j] = (d == c0 + j) ? 0.0f : __fdiv_rn(1.0f, __fadd_rn(dist[j], 1e-10f));

    __shared__ float wmax[TCE][4];
    const int wave = threadIdx.x >> 6;
    const int lane = threadIdx.x & 63;
#pragma unroll
    for (int j = 0; j < TCE; ++j) {
        float v = ed[j];
#pragma unroll
        for (int m = 1; m < 64; m <<= 1) v = fmaxf(v, __shfl_xor(v, m));
        if (lane == 0) wmax[j][wave] = v;
    }
    __syncthreads();

#pragma unroll
    for (int j = 0; j < TCE; ++j) {
        const int c = c0 + j;
        float em = fmaxf(fmaxf(wmax[j][0], wmax[j][1]), fmaxf(wmax[j][2], wmax[j][3]));
        float p;
        if (d == c) {
            p = 0.99f;
        } else {
            p = __fmul_rn(__fdiv_rn(ed[j], em), 0.99f);
        }
        float logit = logf(__fdiv_rn(p, __fsub_rn(1.0f, p)));

        const float2 g2 = *(const float2*)(gu + (((size_t)b * CC + c) * CC + d) * 2);
        float g0 = -logf(-logf(g2.x));
        float g1 = -logf(-logf(g2.y));

        float a0 = __fadd_rn(logit, g0);
        float a1 = __fadd_rn(-logit, g1);
        float m  = fmaxf(a0, a1);
        float e0 = expf(__fsub_rn(a0, m));
        float e1 = expf(__fsub_rn(a1, m));
        float s  = __fadd_rn(e0, e1);
        float y0 = __fdiv_rn(e0, s);
        float y1 = __fdiv_rn(e1, s);
        if (y0 > y1) {
            atomicAdd(&out[(size_t)c * CC + d], 0.125f);
        }
    }
}

// ---------------- Path B: fused fallback (no ws) — R7 verbatim ----------------

#define STEPU(UC, ACC) {                         \
    float diff = __fsub_rn(UC, ud);              \
    float t    = __fmul_rn(dAd, diff);           \
    float sq   = __fmul_rn(t, t);                \
    ACC = __fadd_rn(ACC, sq);                    \
}

#define LOADG(BA, BP, GIDX) {                    \
    const float* _a = ampbd + (size_t)(GIDX) * 8 * CC; \
    const float* _p = phbd  + (size_t)(GIDX) * 8 * CC; \
    _Pragma("unroll")                            \
    for (int i = 0; i < 8; ++i) {                \
        BA[i] = _a[(size_t)i * CC];              \
        BP[i] = _p[(size_t)i * CC];              \
    }                                            \
}

#define COMPG(BA, BP, GIDX) {                    \
    const int _xb = (GIDX) * 8;                  \
    _Pragma("unroll")                            \
    for (int i = 0; i < 8; ++i) {                \
        const float av = BA[i];                  \
        const float pv = BP[i];                  \
        const float ud = __fadd_rn(__fmul_rn(wa, av), __fmul_rn(wp, pv)); \
        const float4 uc = cols[_xb + i];         \
        STEPU(uc.x, acc0)                        \
        STEPU(uc.y, acc1)                        \
        STEPU(uc.z, acc2)                        \
        STEPU(uc.w, acc3)                        \
    }                                            \
}

__global__ __launch_bounds__(256, 2) void k_fused(
    const float* __restrict__ amp, const float* __restrict__ ph,
    const float* __restrict__ A,   const float* __restrict__ wAp,
    const float* __restrict__ wPp, const float* __restrict__ gu,
    float* __restrict__ out)
{
    const int d  = threadIdx.x;
    const int c0 = blockIdx.x * TCE;
    const int b  = blockIdx.y;

    const float wa = wAp[0];
    const float wp = wPp[0];

    __shared__ float4 cols[XX];
    {
        const int x = threadIdx.x;
        const size_t base = ((size_t)b * XX + x) * CC + c0;
        const float4 a4 = *(const float4*)(amp + base);
        const float4 p4 = *(const float4*)(ph  + base);
        float4 uu;
        uu.x = __fadd_rn(__fmul_rn(wa, a4.x), __fmul_rn(wp, p4.x));
        uu.y = __fadd_rn(__fmul_rn(wa, a4.y), __fmul_rn(wp, p4.y));
        uu.z = __fadd_rn(__fmul_rn(wa, a4.z), __fmul_rn(wp, p4.z));
        uu.w = __fadd_rn(__fmul_rn(wa, a4.w), __fmul_rn(wp, p4.w));
        cols[x] = uu;
    }
    __syncthreads();

    const float dAd = A[(size_t)d * CC + d];
    const float* ampbd = amp + (size_t)b * XX * CC + d;
    const float* phbd  = ph  + (size_t)b * XX * CC + d;

    float acc0 = 0.0f, acc1 = 0.0f, acc2 = 0.0f, acc3 = 0.0f;
    constexpr int NG = XX / 8;
    {
        float b0A[8], b0P[8], b1A[8], b1P[8];
        LOADG(b0A, b0P, 0)
        for (int g = 0; g + 2 < NG; g += 2) {
            LOADG(b1A, b1P, g + 1)
            COMPG(b0A, b0P, g)
            LOADG(b0A, b0P, g + 2)
            COMPG(b1A, b1P, g + 1)
        }
        LOADG(b1A, b1P, NG - 1)
        COMPG(b0A, b0P, NG - 2)
        COMPG(b1A, b1P, NG - 1)
    }

    float ed[TCE];
    ed[0] = (d == c0)     ? 0.0f : __fdiv_rn(1.0f, __fadd_rn(acc0, 1e-10f));
    ed[1] = (d == c0 + 1) ? 0.0f : __fdiv_rn(1.0f, __fadd_rn(acc1, 1e-10f));
    ed[2] = (d == c0 + 2) ? 0.0f : __fdiv_rn(1.0f, __fadd_rn(acc2, 1e-10f));
    ed[3] = (d == c0 + 3) ? 0.0f : __fdiv_rn(1.0f, __fadd_rn(acc3, 1e-10f));

    __shared__ float wmax[TCE][4];
    const int wave = threadIdx.x >> 6;
    const int lane = threadIdx.x & 63;
#pragma unroll
    for (int j = 0; j < TCE; ++j) {
        float v = ed[j];
#pragma unroll
        for (int m = 1; m < 64; m <<= 1) v = fmaxf(v, __shfl_xor(v, m));
        if (lane == 0) wmax[j][wave] = v;
    }
    __syncthreads();

#pragma unroll
    for (int j = 0; j < TCE; ++j) {
        const int c = c0 + j;
        float em = fmaxf(fmaxf(wmax[j][0], wmax[j][1]), fmaxf(wmax[j][2], wmax[j][3]));
        float p;
        if (d == c) {
            p = 0.99f;
        } else {
            p = __fmul_rn(__fdiv_rn(ed[j], em), 0.99f);
        }
        float logit = logf(__fdiv_rn(p, __fsub_rn(1.0f, p)));

        const float2 g2 = *(const float2*)(gu + (((size_t)b * CC + c) * CC + d) * 2);
        float g0 = -logf(-logf(g2.x));
        float g1 = -logf(-logf(g2.y));

        float a0 = __fadd_rn(logit, g0);
        float a1 = __fadd_rn(-logit, g1);
        float m  = fmaxf(a0, a1);
        float e0 = expf(__fsub_rn(a0, m));
        float e1 = expf(__fsub_rn(a1, m));
        float s  = __fadd_rn(e0, e1);
        float y0 = __fdiv_rn(e0, s);
        float y1 = __fdiv_rn(e1, s);
        if (y0 > y1) {
            atomicAdd(&out[(size_t)c * CC + d], 0.125f);
        }
    }
}

extern "C" void kernel_launch(void* const* d_in, const int* in_sizes, int n_in,
                              void* d_out, int out_size, void* d_ws, size_t ws_size,
                              hipStream_t stream) {
    const float* amp = (const float*)d_in[0];
    const float* ph  = (const float*)d_in[1];
    const float* A   = (const float*)d_in[2];
    const float* wa  = (const float*)d_in[3];
    const float* wp  = (const float*)d_in[4];
    const float* gu  = (const float*)d_in[5];
    float* out = (float*)d_out;

    const size_t uElems = (size_t)BB * XX * CC;                    // 2 MB
    const size_t pElems = (size_t)SPLIT * BB * CC * CC;            // 8 MB
    const size_t need = (uElems + pElems) * sizeof(float);
    if (ws_size >= need) {
        float* ud  = (float*)d_ws;          // fully written by k_u
        float* wsd = ud + uElems;           // fully written by k_dist
        k_u<<<uElems / 4 / 256, 256, 0, stream>>>(amp, ph, wa, wp, ud, out);
        dim3 g1(CC / TCD, BB);
        k_dist<<<g1, 256, 0, stream>>>(ud, wsd);
        dim3 g2(CC / TCE, BB);
        k_epi<<<g2, 256, 0, stream>>>(wsd, A, gu, out);
    } else {
        hipMemsetAsync(out, 0, (size_t)CC * CC * sizeof(float), stream);
        dim3 g(CC / TCE, BB);
        k_fused<<<g, 256, 0, stream>>>(amp, ph, A, wa, wp, gu, out);
    }
}

// Round 12
// 84.147 us; speedup vs baseline: 1.1151x; 1.0690x over previous
//
#include <hip/hip_runtime.h>

#define BB 8
#define XX 256
#define CC 256
#define TCD 8         // c-rows per k_dist block (amortize d-loads over 8 c's)
#define TCE 4         // c-rows per k_epi block
#define TD 4          // d's per lane -> b128 d-loads, wave covers all 256 d
#define SPLIT 8       // x-chunks of 32 (wave-sized)
#define XHW 32        // x's per wave-chunk
#define GX 4          // x-group for register double-buffer

// R12: the R11 post-mortem algebra — d-side traffic = (256/TCc) x 2 MB,
// d-load instrs = waves x x/wave. R7 had TCc=8 (64 MB) but scalar loads
// (262k instr); R11 had TD=4 (65k instr) but TCc=2 (256 MB). This round:
// TD=4 AND TCc=8 -> 65k b128 loads, 64 MB, 36 FMA per 3 mem-instr per x.
// k_u folded in (u computed inline, bitwise-same _rn formula); out zeroed
// by k_dist's bz==0,by==0 blocks -> 2 dispatches. Chunks of 32 x + 8-way
// sequential combine = same ulp-class as R10's 16-x chunks (absmax 0.0).

// ---------------- k_dist: fused u + Gram partials ----------------

#define AULOAD(BA, BP, GIDX) {                                    \
    const float* _a = ampbd + (size_t)(GIDX) * GX * CC;           \
    const float* _p = phbd  + (size_t)(GIDX) * GX * CC;           \
    _Pragma("unroll")                                             \
    for (int i = 0; i < GX; ++i) {                                \
        BA[i] = *(const float4*)(_a + (size_t)i * CC);            \
        BP[i] = *(const float4*)(_p + (size_t)i * CC);            \
    } }

#define AUCOMP(BA, BP, GIDX) {                                    \
    const int _xb = xloc + (GIDX) * GX;                           \
    _Pragma("unroll")                                             \
    for (int i = 0; i < GX; ++i) {                                \
        const float4 a4 = BA[i];                                  \
        const float4 p4 = BP[i];                                  \
        float4 ud4;                                               \
        ud4.x = __fadd_rn(__fmul_rn(wa, a4.x), __fmul_rn(wp, p4.x)); \
        ud4.y = __fadd_rn(__fmul_rn(wa, a4.y), __fmul_rn(wp, p4.y)); \
        ud4.z = __fadd_rn(__fmul_rn(wa, a4.z), __fmul_rn(wp, p4.z)); \
        ud4.w = __fadd_rn(__fmul_rn(wa, a4.w), __fmul_rn(wp, p4.w)); \
        const float4 cA = cols[_xb + i][0];                       \
        const float4 cB = cols[_xb + i][1];                       \
        _Pragma("unroll")                                         \
        for (int k = 0; k < 4; ++k) {                             \
            const float uv = (k==0)?ud4.x:(k==1)?ud4.y:(k==2)?ud4.z:ud4.w; \
            g[0][k] = fmaf(cA.x, uv, g[0][k]);                    \
            g[1][k] = fmaf(cA.y, uv, g[1][k]);                    \
            g[2][k] = fmaf(cA.z, uv, g[2][k]);                    \
            g[3][k] = fmaf(cA.w, uv, g[3][k]);                    \
            g[4][k] = fmaf(cB.x, uv, g[4][k]);                    \
            g[5][k] = fmaf(cB.y, uv, g[5][k]);                    \
            g[6][k] = fmaf(cB.z, uv, g[6][k]);                    \
            g[7][k] = fmaf(cB.w, uv, g[7][k]);                    \
            s[k]    = fmaf(uv, uv, s[k]);                         \
        }                                                         \
    } }

__global__ __launch_bounds__(256, 2) void k_dist(
    const float* __restrict__ amp, const float* __restrict__ ph,
    const float* __restrict__ wAp, const float* __restrict__ wPp,
    float* __restrict__ wsd,          // [SPLIT][B][C][C] partials
    float* __restrict__ out)          // zeroed by bz==0,by==0 blocks
{
    const int tid   = threadIdx.x;
    const int lane  = tid & 63;
    const int w     = tid >> 6;             // wave 0..3
    const int c0    = blockIdx.x * TCD;
    const int b     = blockIdx.y;
    const int xhalf = blockIdx.z * 128;     // this block's 128-x window
    const int cz    = blockIdx.z * 4 + w;   // chunk id 0..7
    const int xloc  = w * XHW;              // wave's x-offset in window
    const int d0    = lane * TD;

    // zero out (before k_epi's atomics; k_epi is a later dispatch)
    if (blockIdx.y == 0 && blockIdx.z == 0) {
        ((float4*)out)[blockIdx.x * 512 + tid]       = make_float4(0.f,0.f,0.f,0.f);
        ((float4*)out)[blockIdx.x * 512 + 256 + tid] = make_float4(0.f,0.f,0.f,0.f);
    }

    const float wa = wAp[0], wp = wPp[0];

    // stage cols[x][h] = u[b, xhalf+x, c0+4h .. c0+4h+3]  (u bitwise = k_u's)
    __shared__ float4 cols[128][2];         // 4 KB
    {
        const int x = tid >> 1, h = tid & 1;
        const size_t base = ((size_t)b * XX + xhalf + x) * CC + c0 + 4 * h;
        const float4 a4 = *(const float4*)(amp + base);
        const float4 p4 = *(const float4*)(ph  + base);
        float4 uu;
        uu.x = __fadd_rn(__fmul_rn(wa, a4.x), __fmul_rn(wp, p4.x));
        uu.y = __fadd_rn(__fmul_rn(wa, a4.y), __fmul_rn(wp, p4.y));
        uu.z = __fadd_rn(__fmul_rn(wa, a4.z), __fmul_rn(wp, p4.z));
        uu.w = __fadd_rn(__fmul_rn(wa, a4.w), __fmul_rn(wp, p4.w));
        cols[x][h] = uu;
    }
    __syncthreads();

    const float* ampbd = amp + ((size_t)b * XX + xhalf + xloc) * CC + d0;
    const float* phbd  = ph  + ((size_t)b * XX + xhalf + xloc) * CC + d0;

    float g[TCD][4];
#pragma unroll
    for (int j = 0; j < TCD; ++j)
#pragma unroll
        for (int k = 0; k < 4; ++k) g[j][k] = 0.0f;
    float s[4] = {0.f, 0.f, 0.f, 0.f};

    constexpr int NG = XHW / GX;            // 8 groups of 4 x
    {
        float4 b0A[GX], b0P[GX], b1A[GX], b1P[GX];
        AULOAD(b0A, b0P, 0)
        for (int gg = 0; gg + 2 < NG; gg += 2) {
            AULOAD(b1A, b1P, gg + 1)
            AUCOMP(b0A, b0P, gg)
            AULOAD(b0A, b0P, gg + 2)
            AUCOMP(b1A, b1P, gg + 1)
        }
        AULOAD(b1A, b1P, NG - 1)
        AUCOMP(b0A, b0P, NG - 2)
        AUCOMP(b1A, b1P, NG - 1)
    }

    // per-chunk S exchange
    __shared__ float sS[4][CC];             // 4 KB
    *(float4*)&sS[w][d0] = make_float4(s[0], s[1], s[2], s[3]);
    __syncthreads();

    // partial = fmaf(-2, G, S_c + S_d), coalesced b128 stores
    float* wbase = wsd + (((size_t)cz * BB + b) * CC + c0) * CC + d0;
#pragma unroll
    for (int j = 0; j < TCD; ++j) {
        const float scj = sS[w][c0 + j];
        float4 o;
        o.x = fmaf(-2.0f, g[j][0], __fadd_rn(scj, s[0]));
        o.y = fmaf(-2.0f, g[j][1], __fadd_rn(scj, s[1]));
        o.z = fmaf(-2.0f, g[j][2], __fadd_rn(scj, s[2]));
        o.w = fmaf(-2.0f, g[j][3], __fadd_rn(scj, s[3]));
        *(float4*)(wbase + (size_t)j * CC) = o;
    }
}

// ---------------- k_epi: R7 structure, SPLIT=8 ----------------

__global__ __launch_bounds__(256, 4) void k_epi(
    const float* __restrict__ wsd, const float* __restrict__ A,
    const float* __restrict__ gu,  float* __restrict__ out)
{
    const int d  = threadIdx.x;
    const int c0 = blockIdx.x * TCE;
    const int b  = blockIdx.y;

    const float dAd  = A[(size_t)d * CC + d];
    const float dAd2 = __fmul_rn(dAd, dAd);

    float dist[TCE];
#pragma unroll
    for (int j = 0; j < TCE; ++j) {
        const size_t ro = ((size_t)b * CC + c0 + j) * CC + d;
        float p = wsd[ro];                                    // chunk 0
#pragma unroll
        for (int h = 1; h < SPLIT; ++h)
            p = __fadd_rn(p, wsd[(size_t)h * BB * CC * CC + ro]);
        dist[j] = __fmul_rn(dAd2, p);
    }

    float ed[TCE];
#pragma unroll
    for (int j = 0; j < TCE; ++j)
        ed[j] = (d == c0 + j) ? 0.0f : __fdiv_rn(1.0f, __fadd_rn(dist[j], 1e-10f));

    __shared__ float wmax[TCE][4];
    const int wave = threadIdx.x >> 6;
    const int lane = threadIdx.x & 63;
#pragma unroll
    for (int j = 0; j < TCE; ++j) {
        float v = ed[j];
#pragma unroll
        for (int m = 1; m < 64; m <<= 1) v = fmaxf(v, __shfl_xor(v, m));
        if (lane == 0) wmax[j][wave] = v;
    }
    __syncthreads();

#pragma unroll
    for (int j = 0; j < TCE; ++j) {
        const int c = c0 + j;
        float em = fmaxf(fmaxf(wmax[j][0], wmax[j][1]), fmaxf(wmax[j][2], wmax[j][3]));
        float p;
        if (d == c) {
            p = 0.99f;
        } else {
            p = __fmul_rn(__fdiv_rn(ed[j], em), 0.99f);
        }
        float logit = logf(__fdiv_rn(p, __fsub_rn(1.0f, p)));

        const float2 g2 = *(const float2*)(gu + (((size_t)b * CC + c) * CC + d) * 2);
        float g0 = -logf(-logf(g2.x));
        float g1 = -logf(-logf(g2.y));

        float a0 = __fadd_rn(logit, g0);
        float a1 = __fadd_rn(-logit, g1);
        float m  = fmaxf(a0, a1);
        float e0 = expf(__fsub_rn(a0, m));
        float e1 = expf(__fsub_rn(a1, m));
        float sm = __fadd_rn(e0, e1);
        float y0 = __fdiv_rn(e0, sm);
        float y1 = __fdiv_rn(e1, sm);
        if (y0 > y1) {
            atomicAdd(&out[(size_t)c * CC + d], 0.125f);
        }
    }
}

// ---------------- Path B: fused fallback (no ws) — R7 verbatim ----------------

#define STEPU(UC, ACC) {                         \
    float diff = __fsub_rn(UC, ud);              \
    float t    = __fmul_rn(dAd, diff);           \
    float sq   = __fmul_rn(t, t);                \
    ACC = __fadd_rn(ACC, sq);                    \
}

#define LOADG(BA, BP, GIDX) {                    \
    const float* _a = ampbd + (size_t)(GIDX) * 8 * CC; \
    const float* _p = phbd  + (size_t)(GIDX) * 8 * CC; \
    _Pragma("unroll")                            \
    for (int i = 0; i < 8; ++i) {                \
        BA[i] = _a[(size_t)i * CC];              \
        BP[i] = _p[(size_t)i * CC];              \
    }                                            \
}

#define COMPG(BA, BP, GIDX) {                    \
    const int _xb = (GIDX) * 8;                  \
    _Pragma("unroll")                            \
    for (int i = 0; i < 8; ++i) {                \
        const float av = BA[i];                  \
        const float pv = BP[i];                  \
        const float ud = __fadd_rn(__fmul_rn(wa, av), __fmul_rn(wp, pv)); \
        const float4 uc = cols[_xb + i];         \
        STEPU(uc.x, acc0)                        \
        STEPU(uc.y, acc1)                        \
        STEPU(uc.z, acc2)                        \
        STEPU(uc.w, acc3)                        \
    }                                            \
}

__global__ __launch_bounds__(256, 2) void k_fused(
    const float* __restrict__ amp, const float* __restrict__ ph,
    const float* __restrict__ A,   const float* __restrict__ wAp,
    const float* __restrict__ wPp, const float* __restrict__ gu,
    float* __restrict__ out)
{
    const int d  = threadIdx.x;
    const int c0 = blockIdx.x * TCE;
    const int b  = blockIdx.y;

    const float wa = wAp[0];
    const float wp = wPp[0];

    __shared__ float4 cols[XX];
    {
        const int x = threadIdx.x;
        const size_t base = ((size_t)b * XX + x) * CC + c0;
        const float4 a4 = *(const float4*)(amp + base);
        const float4 p4 = *(const float4*)(ph  + base);
        float4 uu;
        uu.x = __fadd_rn(__fmul_rn(wa, a4.x), __fmul_rn(wp, p4.x));
        uu.y = __fadd_rn(__fmul_rn(wa, a4.y), __fmul_rn(wp, p4.y));
        uu.z = __fadd_rn(__fmul_rn(wa, a4.z), __fmul_rn(wp, p4.z));
        uu.w = __fadd_rn(__fmul_rn(wa, a4.w), __fmul_rn(wp, p4.w));
        cols[x] = uu;
    }
    __syncthreads();

    const float dAd = A[(size_t)d * CC + d];
    const float* ampbd = amp + (size_t)b * XX * CC + d;
    const float* phbd  = ph  + (size_t)b * XX * CC + d;

    float acc0 = 0.0f, acc1 = 0.0f, acc2 = 0.0f, acc3 = 0.0f;
    constexpr int NG = XX / 8;
    {
        float b0A[8], b0P[8], b1A[8], b1P[8];
        LOADG(b0A, b0P, 0)
        for (int g = 0; g + 2 < NG; g += 2) {
            LOADG(b1A, b1P, g + 1)
            COMPG(b0A, b0P, g)
            LOADG(b0A, b0P, g + 2)
            COMPG(b1A, b1P, g + 1)
        }
        LOADG(b1A, b1P, NG - 1)
        COMPG(b0A, b0P, NG - 2)
        COMPG(b1A, b1P, NG - 1)
    }

    float ed[TCE];
    ed[0] = (d == c0)     ? 0.0f : __fdiv_rn(1.0f, __fadd_rn(acc0, 1e-10f));
    ed[1] = (d == c0 + 1) ? 0.0f : __fdiv_rn(1.0f, __fadd_rn(acc1, 1e-10f));
    ed[2] = (d == c0 + 2) ? 0.0f : __fdiv_rn(1.0f, __fadd_rn(acc2, 1e-10f));
    ed[3] = (d == c0 + 3) ? 0.0f : __fdiv_rn(1.0f, __fadd_rn(acc3, 1e-10f));

    __shared__ float wmax[TCE][4];
    const int wave = threadIdx.x >> 6;
    const int lane = threadIdx.x & 63;
#pragma unroll
    for (int j = 0; j < TCE; ++j) {
        float v = ed[j];
#pragma unroll
        for (int m = 1; m < 64; m <<= 1) v = fmaxf(v, __shfl_xor(v, m));
        if (lane == 0) wmax[j][wave] = v;
    }
    __syncthreads();

#pragma unroll
    for (int j = 0; j < TCE; ++j) {
        const int c = c0 + j;
        float em = fmaxf(fmaxf(wmax[j][0], wmax[j][1]), fmaxf(wmax[j][2], wmax[j][3]));
        float p;
        if (d == c) {
            p = 0.99f;
        } else {
            p = __fmul_rn(__fdiv_rn(ed[j], em), 0.99f);
        }
        float logit = logf(__fdiv_rn(p, __fsub_rn(1.0f, p)));

        const float2 g2 = *(const float2*)(gu + (((size_t)b * CC + c) * CC + d) * 2);
        float g0 = -logf(-logf(g2.x));
        float g1 = -logf(-logf(g2.y));

        float a0 = __fadd_rn(logit, g0);
        float a1 = __fadd_rn(-logit, g1);
        float m  = fmaxf(a0, a1);
        float e0 = expf(__fsub_rn(a0, m));
        float e1 = expf(__fsub_rn(a1, m));
        float sm = __fadd_rn(e0, e1);
        float y0 = __fdiv_rn(e0, sm);
        float y1 = __fdiv_rn(e1, sm);
        if (y0 > y1) {
            atomicAdd(&out[(size_t)c * CC + d], 0.125f);
        }
    }
}

extern "C" void kernel_launch(void* const* d_in, const int* in_sizes, int n_in,
                              void* d_out, int out_size, void* d_ws, size_t ws_size,
                              hipStream_t stream) {
    const float* amp = (const float*)d_in[0];
    const float* ph  = (const float*)d_in[1];
    const float* A   = (const float*)d_in[2];
    const float* wa  = (const float*)d_in[3];
    const float* wp  = (const float*)d_in[4];
    const float* gu  = (const float*)d_in[5];
    float* out = (float*)d_out;

    const size_t pElems = (size_t)SPLIT * BB * CC * CC;            // 16.8 MB
    const size_t need = pElems * sizeof(float);
    if (ws_size >= need) {
        float* wsd = (float*)d_ws;          // fully written by k_dist
        dim3 g1(CC / TCD, BB, 2);
        k_dist<<<g1, 256, 0, stream>>>(amp, ph, wa, wp, wsd, out);
        dim3 g2(CC / TCE, BB);
        k_epi<<<g2, 256, 0, stream>>>(wsd, A, gu, out);
    } else {
        hipMemsetAsync(out, 0, (size_t)CC * CC * sizeof(float), stream);
        dim3 g(CC / TCE, BB);
        k_fused<<<g, 256, 0, stream>>>(amp, ph, A, wa, wp, gu, out);
    }
}